// Round 1
// baseline (214.444 us; speedup 1.0000x reference)
//
#include <hip/hip_runtime.h>
#include <hip/hip_bf16.h>
#include <math.h>

// Problem constants (fixed by setup_inputs / reference)
#define B_      16
#define C_IN    64
#define FEAT_C_ 8
#define H_      112
#define W_      112
#define NH_     16      // H/7
#define NW_     16      // W/7
#define NPTS    100
#define P_      49      // 7*7
#define PLANE   (H_*W_) // 12544

// ---------------------------------------------------------------------------
// Kernel 0: zero the lbar-sum accumulator in workspace (ws is poisoned 0xAA).
// ---------------------------------------------------------------------------
__global__ void zero_kernel(float* __restrict__ S) {
    int i = blockIdx.x * 256 + threadIdx.x;
    if (i < P_ * NPTS) S[i] = 0.0f;
}

// ---------------------------------------------------------------------------
// Kernel 1: S[p][n] = sum over (b, nh, nw) of logits[b, n, 7*nh + r, 7*nw + c]
// with p = r*7 + c.  One block per (b, n, r): reads 16 rows x 112 cols.
// Per-thread register accumulation (column c is constant per thread), then
// 7 LDS bins, then 7 global float atomicAdds.  Total atomics: 11200*7 = 78.4k.
// ---------------------------------------------------------------------------
__global__ __launch_bounds__(64) void reduce_kernel(const float* __restrict__ logits,
                                                    float* __restrict__ S) {
    int blk = blockIdx.x;          // [0, 16*100*7)
    int r   = blk % 7;
    int bn  = blk / 7;             // b*100 + n
    const float* plane = logits + (size_t)bn * PLANE;

    int t = threadIdx.x;           // 0..63
    float acc0 = 0.0f, acc1 = 0.0f;
    #pragma unroll
    for (int k = 0; k < 16; ++k) {
        const float* row = plane + (r + 7 * k) * W_;
        acc0 += row[t];
        if (t < 48) acc1 += row[t + 64];
    }

    __shared__ float bins[7];
    if (t < 7) bins[t] = 0.0f;
    __syncthreads();
    atomicAdd(&bins[t % 7], acc0);
    if (t < 48) atomicAdd(&bins[(t + 64) % 7], acc1);
    __syncthreads();

    if (t < 7) {
        int n = bn % NPTS;
        int p = r * 7 + t;
        atomicAdd(&S[p * NPTS + n], bins[t]);
    }
}

// ---------------------------------------------------------------------------
// Kernel 2: per-p weight construction.  49 active threads in one block.
// Produces WtT[q*49 + p] = wop[p] * kT[p][i][j]  (q = i*7 + j).
// ---------------------------------------------------------------------------
__global__ void weights_kernel(const float* __restrict__ S,
                               const float* __restrict__ sigx,
                               const float* __restrict__ sigy,
                               const float* __restrict__ opac,
                               const float* __restrict__ rho,
                               float* __restrict__ WtT) {
    int p = threadIdx.x;
    if (p >= P_) return;

    float wsx = 0.0f, wsy = 0.0f, wop = 0.0f, wrho = 0.0f;
    for (int n = 0; n < NPTS; ++n) {
        float l = S[p * NPTS + n] * (1.0f / 4096.0f);   // mean over 16*16*16 patches
        wsx  += l * sigx[n];
        wsy  += l * sigy[n];
        wop  += l * opac[n];
        wrho += l * rho[n];
    }

    float a   = wsx * wsx + 1e-5f;
    float d   = wsy * wsy + 1e-5f;
    float b   = wrho * wsx * wsy;
    float det = a * d - b * b;
    float ia  = d / det, ib = -b / det, idd = a / det;

    // 5x5 gaussian on linspace(-5,5,5); the 1/(2*pi*sqrt(det)) factor cancels
    // under max-normalization (quadratic form is PSD so max is at center, but
    // compute the max explicitly to match the reference semantics).
    float k5[25];
    float kmax = -1e30f;
    #pragma unroll
    for (int i = 0; i < 5; ++i) {
        float x = -5.0f + 2.5f * (float)i;
        #pragma unroll
        for (int j = 0; j < 5; ++j) {
            float y = -5.0f + 2.5f * (float)j;
            float z = -0.5f * (ia * x * x + 2.0f * ib * x * y + idd * y * y);
            float v = expf(z);
            k5[i * 5 + j] = v;
            kmax = fmaxf(kmax, v);
        }
    }

    // pad to 7x7 (1-px border of zeros)
    float k7[7][7];
    #pragma unroll
    for (int i = 0; i < 7; ++i)
        #pragma unroll
        for (int j = 0; j < 7; ++j) k7[i][j] = 0.0f;
    #pragma unroll
    for (int i = 0; i < 5; ++i)
        #pragma unroll
        for (int j = 0; j < 5; ++j) k7[i + 1][j + 1] = k5[i * 5 + j] / kmax;

    // bilinear translate by (sx, sy); zero outside [0,6]
    int r = p / 7, c = p % 7;
    float sx = 3.0f - (6.0f / 7.0f) * (float)c;   // tx*(COL-1)/2
    float sy = 3.0f - (6.0f / 7.0f) * (float)r;   // ty*(ROW-1)/2

    for (int i = 0; i < 7; ++i) {
        float ii = (float)i + sy;
        float fi0 = floorf(ii);
        int   i0  = (int)fi0;
        float wi  = ii - fi0;
        for (int j = 0; j < 7; ++j) {
            float jj  = (float)j + sx;
            float fj0 = floorf(jj);
            int   j0  = (int)fj0;
            float wj  = jj - fj0;

            bool iv0 = (i0 >= 0)     && (i0 <= 6);
            bool iv1 = (i0 + 1 >= 0) && (i0 + 1 <= 6);
            bool jv0 = (j0 >= 0)     && (j0 <= 6);
            bool jv1 = (j0 + 1 >= 0) && (j0 + 1 <= 6);
            int ci0 = min(max(i0, 0), 6),     cj0 = min(max(j0, 0), 6);
            int ci1 = min(max(i0 + 1, 0), 6), cj1 = min(max(j0 + 1, 0), 6);

            float v00 = (iv0 && jv0) ? k7[ci0][cj0] : 0.0f;
            float v01 = (iv0 && jv1) ? k7[ci0][cj1] : 0.0f;
            float v10 = (iv1 && jv0) ? k7[ci1][cj0] : 0.0f;
            float v11 = (iv1 && jv1) ? k7[ci1][cj1] : 0.0f;

            float kt = v00 * (1.0f - wi) * (1.0f - wj)
                     + v01 * (1.0f - wi) * wj
                     + v10 * wi * (1.0f - wj)
                     + v11 * wi * wj;

            WtT[(i * 7 + j) * P_ + p] = wop * kt;
        }
    }
}

// ---------------------------------------------------------------------------
// Kernel 3: out[b, ch, 7*nh + i, 7*nw + j] =
//              sum_p feat[b, ch, 7*nh + p_r, 7*nw + p_c] * WtT[(i*7+j)*49 + p]
// One lane per 7x7 block (32768 blocks total).  The 49 inputs live in VGPRs;
// WtT accesses are wave-uniform (q, p compile-time / uniform loop counters)
// so the compiler emits scalar loads -> v_fmac with SGPR operand.
// ---------------------------------------------------------------------------
__global__ __launch_bounds__(64) void apply_kernel(const float* __restrict__ inp,
                                                   const float* __restrict__ WtT,
                                                   float* __restrict__ out) {
    int bl = blockIdx.x * 64 + threadIdx.x;  // [0, 32768)
    int nw = bl & 15;
    int t  = bl >> 4;
    int nh = t & 15;
    t >>= 4;
    int ch    = t & 7;
    int batch = t >> 3;

    const float* src = inp + (((size_t)batch * C_IN   + ch) * H_ + nh * 7) * W_ + nw * 7;
    float*       dst = out + (((size_t)batch * FEAT_C_ + ch) * H_ + nh * 7) * W_ + nw * 7;

    float in[P_];
    #pragma unroll
    for (int r = 0; r < 7; ++r)
        #pragma unroll
        for (int c = 0; c < 7; ++c)
            in[r * 7 + c] = src[r * W_ + c];

    for (int q = 0; q < P_; ++q) {
        const float* w = WtT + q * P_;
        float acc = 0.0f;
        #pragma unroll
        for (int p = 0; p < P_; ++p) acc += in[p] * w[p];
        dst[(q / 7) * W_ + (q % 7)] = acc;
    }
}

// ---------------------------------------------------------------------------
extern "C" void kernel_launch(void* const* d_in, const int* in_sizes, int n_in,
                              void* d_out, int out_size, void* d_ws, size_t ws_size,
                              hipStream_t stream) {
    const float* inp    = (const float*)d_in[0];  // (16, 64, 112, 112)
    const float* logits = (const float*)d_in[1];  // (16, 100, 112, 112)
    const float* sigx   = (const float*)d_in[2];  // (100,)
    const float* sigy   = (const float*)d_in[3];  // (100,)
    const float* opac   = (const float*)d_in[4];  // (100,1) flat
    const float* rho    = (const float*)d_in[5];  // (100,1) flat
    // d_in[6] = scale (unused by reference)

    float* out = (float*)d_out;                   // (16, 8, 112, 112) f32
    float* S   = (float*)d_ws;                    // 49*100 floats
    float* WtT = S + P_ * NPTS;                   // 49*49 floats

    zero_kernel<<<(P_ * NPTS + 255) / 256, 256, 0, stream>>>(S);
    reduce_kernel<<<B_ * NPTS * 7, 64, 0, stream>>>(logits, S);
    weights_kernel<<<1, 64, 0, stream>>>(S, sigx, sigy, opac, rho, WtT);
    apply_kernel<<<(B_ * FEAT_C_ * NH_ * NW_) / 64, 64, 0, stream>>>(inp, WtT, out);
}

// Round 2
// 194.050 us; speedup vs baseline: 1.1051x; 1.1051x over previous
//
#include <hip/hip_runtime.h>
#include <hip/hip_bf16.h>
#include <math.h>

// Problem constants (fixed by setup_inputs / reference)
#define B_      16
#define C_IN    64
#define FEAT_C_ 8
#define H_      112
#define W_      112
#define NH_     16      // H/7
#define NW_     16      // W/7
#define NPTS    100
#define P_      49      // 7*7
#define PLANE   (H_*W_) // 12544

// ---------------------------------------------------------------------------
// Kernel 0: zero the lbar-sum accumulator in workspace (ws is poisoned 0xAA).
// ---------------------------------------------------------------------------
__global__ void zero_kernel(float* __restrict__ S) {
    int i = blockIdx.x * 256 + threadIdx.x;
    if (i < P_ * NPTS) S[i] = 0.0f;
}

// ---------------------------------------------------------------------------
// Kernel 1: S[p][n] = sum over (b, nh, nw) of logits[b, n, 7*nh + r, 7*nw + c]
// with p = r*7 + c.  One block per (b, n, r): reads 16 rows x 112 cols.
// ---------------------------------------------------------------------------
__global__ __launch_bounds__(64) void reduce_kernel(const float* __restrict__ logits,
                                                    float* __restrict__ S) {
    int blk = blockIdx.x;          // [0, 16*100*7)
    int r   = blk % 7;
    int bn  = blk / 7;             // b*100 + n
    const float* plane = logits + (size_t)bn * PLANE;

    int t = threadIdx.x;           // 0..63
    float acc0 = 0.0f, acc1 = 0.0f;
    #pragma unroll
    for (int k = 0; k < 16; ++k) {
        const float* row = plane + (r + 7 * k) * W_;
        acc0 += row[t];
        if (t < 48) acc1 += row[t + 64];
    }

    __shared__ float bins[7];
    if (t < 7) bins[t] = 0.0f;
    __syncthreads();
    atomicAdd(&bins[t % 7], acc0);
    if (t < 48) atomicAdd(&bins[(t + 64) % 7], acc1);
    __syncthreads();

    if (t < 7) {
        int n = bn % NPTS;
        int p = r * 7 + t;
        atomicAdd(&S[p * NPTS + n], bins[t]);
    }
}

// ---------------------------------------------------------------------------
// Kernel 2 (REWRITTEN): per-p weight construction, one 256-thread block.
// Phase 1: 49 threads build per-p params + normalized padded 7x7 kernel in LDS
//          (LDS tolerates dynamic indexing -- no scratch spill, unlike R1).
// Phase 2: 2401 (p,q) bilinear-translate items across 256 threads (4 waves).
// Produces WtT[q*49 + p] = wop[p] * kT[p][i][j]  (q = i*7 + j).
// ---------------------------------------------------------------------------
__global__ __launch_bounds__(256) void weights_kernel(const float* __restrict__ S,
                                                      const float* __restrict__ sigx,
                                                      const float* __restrict__ sigy,
                                                      const float* __restrict__ opac,
                                                      const float* __restrict__ rho,
                                                      float* __restrict__ WtT) {
    __shared__ float k7n[P_][P_ + 1];   // [p][i*7+j], normalized padded kernel
    __shared__ float wopS[P_];

    int t = threadIdx.x;

    if (t < P_) {
        // --- weighted sums over the 100 points ---
        float wsx = 0.0f, wsy = 0.0f, wop = 0.0f, wrho = 0.0f;
        const float* Sp = S + t * NPTS;
        #pragma unroll
        for (int n = 0; n < NPTS; ++n) {
            float l = Sp[n] * (1.0f / 4096.0f);   // mean over 16*16*16 patches
            wsx  += l * sigx[n];
            wsy  += l * sigy[n];
            wop  += l * opac[n];
            wrho += l * rho[n];
        }
        wopS[t] = wop;

        float a   = wsx * wsx + 1e-5f;
        float d   = wsy * wsy + 1e-5f;
        float b   = wrho * wsx * wsy;
        float det = a * d - b * b;
        float ia  = d / det, ib = -b / det, idd = a / det;

        // 5x5 gaussian on linspace(-5,5,5); 1/(2*pi*sqrt(det)) cancels under
        // max-normalization.  Static indexing only -> stays in registers.
        float k5[25];
        float kmax = -1e30f;
        #pragma unroll
        for (int i = 0; i < 5; ++i) {
            float x = -5.0f + 2.5f * (float)i;
            #pragma unroll
            for (int j = 0; j < 5; ++j) {
                float y = -5.0f + 2.5f * (float)j;
                float z = -0.5f * (ia * x * x + 2.0f * ib * x * y + idd * y * y);
                float v = expf(z);
                k5[i * 5 + j] = v;
                kmax = fmaxf(kmax, v);
            }
        }
        float inv = 1.0f / kmax;

        // padded 7x7 (1-px zero border) straight into LDS
        #pragma unroll
        for (int q = 0; q < P_; ++q) k7n[t][q] = 0.0f;
        #pragma unroll
        for (int i = 0; i < 5; ++i)
            #pragma unroll
            for (int j = 0; j < 5; ++j)
                k7n[t][(i + 1) * 7 + (j + 1)] = k5[i * 5 + j] * inv;
    }
    __syncthreads();

    // --- phase 2: bilinear translate, one (p,q) pair per item ---
    for (int idx = t; idx < P_ * P_; idx += 256) {
        int p = idx / P_;
        int q = idx - p * P_;
        int i = q / 7, j = q % 7;
        int r = p / 7, c = p % 7;

        float sx = 3.0f - (6.0f / 7.0f) * (float)c;   // tx*(COL-1)/2
        float sy = 3.0f - (6.0f / 7.0f) * (float)r;   // ty*(ROW-1)/2

        float ii  = (float)i + sy;
        float jj  = (float)j + sx;
        float fi0 = floorf(ii), fj0 = floorf(jj);
        int   i0  = (int)fi0,   j0  = (int)fj0;
        float wi  = ii - fi0,   wj  = jj - fj0;

        bool iv0 = (i0 >= 0)     && (i0 <= 6);
        bool iv1 = (i0 + 1 >= 0) && (i0 + 1 <= 6);
        bool jv0 = (j0 >= 0)     && (j0 <= 6);
        bool jv1 = (j0 + 1 >= 0) && (j0 + 1 <= 6);
        int ci0 = min(max(i0, 0), 6),     cj0 = min(max(j0, 0), 6);
        int ci1 = min(max(i0 + 1, 0), 6), cj1 = min(max(j0 + 1, 0), 6);

        float v00 = (iv0 && jv0) ? k7n[p][ci0 * 7 + cj0] : 0.0f;
        float v01 = (iv0 && jv1) ? k7n[p][ci0 * 7 + cj1] : 0.0f;
        float v10 = (iv1 && jv0) ? k7n[p][ci1 * 7 + cj0] : 0.0f;
        float v11 = (iv1 && jv1) ? k7n[p][ci1 * 7 + cj1] : 0.0f;

        float kt = v00 * (1.0f - wi) * (1.0f - wj)
                 + v01 * (1.0f - wi) * wj
                 + v10 * wi * (1.0f - wj)
                 + v11 * wi * wj;

        WtT[q * P_ + p] = wopS[p] * kt;
    }
}

// ---------------------------------------------------------------------------
// Kernel 3: out[b, ch, 7*nh + i, 7*nw + j] =
//              sum_p feat[b, ch, 7*nh + p_r, 7*nw + p_c] * WtT[(i*7+j)*49 + p]
// One lane per 7x7 block (32768 blocks total); WtT via wave-uniform scalar
// loads, the 49 inputs in VGPRs.
// ---------------------------------------------------------------------------
__global__ __launch_bounds__(64) void apply_kernel(const float* __restrict__ inp,
                                                   const float* __restrict__ WtT,
                                                   float* __restrict__ out) {
    int bl = blockIdx.x * 64 + threadIdx.x;  // [0, 32768)
    int nw = bl & 15;
    int t  = bl >> 4;
    int nh = t & 15;
    t >>= 4;
    int ch    = t & 7;
    int batch = t >> 3;

    const float* src = inp + (((size_t)batch * C_IN    + ch) * H_ + nh * 7) * W_ + nw * 7;
    float*       dst = out + (((size_t)batch * FEAT_C_ + ch) * H_ + nh * 7) * W_ + nw * 7;

    float in[P_];
    #pragma unroll
    for (int r = 0; r < 7; ++r)
        #pragma unroll
        for (int c = 0; c < 7; ++c)
            in[r * 7 + c] = src[r * W_ + c];

    for (int q = 0; q < P_; ++q) {
        const float* w = WtT + q * P_;
        float acc = 0.0f;
        #pragma unroll
        for (int p = 0; p < P_; ++p) acc += in[p] * w[p];
        dst[(q / 7) * W_ + (q % 7)] = acc;
    }
}

// ---------------------------------------------------------------------------
extern "C" void kernel_launch(void* const* d_in, const int* in_sizes, int n_in,
                              void* d_out, int out_size, void* d_ws, size_t ws_size,
                              hipStream_t stream) {
    const float* inp    = (const float*)d_in[0];  // (16, 64, 112, 112)
    const float* logits = (const float*)d_in[1];  // (16, 100, 112, 112)
    const float* sigx   = (const float*)d_in[2];  // (100,)
    const float* sigy   = (const float*)d_in[3];  // (100,)
    const float* opac   = (const float*)d_in[4];  // (100,1) flat
    const float* rho    = (const float*)d_in[5];  // (100,1) flat
    // d_in[6] = scale (unused by reference)

    float* out = (float*)d_out;                   // (16, 8, 112, 112) f32
    float* S   = (float*)d_ws;                    // 49*100 floats
    float* WtT = S + P_ * NPTS;                   // 49*49 floats

    zero_kernel<<<(P_ * NPTS + 255) / 256, 256, 0, stream>>>(S);
    reduce_kernel<<<B_ * NPTS * 7, 64, 0, stream>>>(logits, S);
    weights_kernel<<<1, 256, 0, stream>>>(S, sigx, sigy, opac, rho, WtT);
    apply_kernel<<<(B_ * FEAT_C_ * NH_ * NW_) / 64, 64, 0, stream>>>(inp, WtT, out);
}